// Round 7
// baseline (486.164 us; speedup 1.0000x reference)
//
#include <hip/hip_runtime.h>
#include <math.h>

typedef float v4 __attribute__((ext_vector_type(4)));
typedef float f32x4 __attribute__((ext_vector_type(4)));
typedef __bf16 bf16x8 __attribute__((ext_vector_type(8)));

#define HD 1024      // hidden dim
#define NB 64        // batch

// ws layout (float offsets)
#define WS_IGT  0         // igT [1024][64]   exp(i-gate), transposed
#define WS_FGT  65536     // fgT [1024][64]   exp(f-gate)
#define WS_QT   131072    // qT  [1024][64]
#define WS_VT   196608    // vT  [1024][64]
#define WS_OGN  262144    // ogN [64][1024]   sigmoid(o), natural
#define WS_KN   327680    // kN  [64][1024]   natural
#define WS_BPK  393216    // bf16 x/h B-fragments [64 ks][4 bt][64 lane][8] = 65536 floats
#define WS_PART 458752    // readout partials [32 rg][64 b][1024] = 2,097,152 floats
// total = 2,555,904 floats = 10.2 MB

// ---------------- kernel 1: pack x/h to bf16 MFMA B-fragments (tiny) ------------
__global__ __launch_bounds__(256) void k_prepb(const float* __restrict__ input,
                                               const float* __restrict__ h,
                                               float* __restrict__ ws) {
    int o = blockIdx.x * 256 + threadIdx.x;     // 0..16383
    int l  = o & 63;
    int bt = (o >> 6) & 3;
    int ks = o >> 8;                            // 0..63
    const float* srcm = (ks < 32) ? input : h;
    const float* src = srcm + (size_t)(bt * 16 + (l & 15)) * HD + (ks & 31) * 32 + (l >> 4) * 8;
    v4 f0 = *(const v4*)src;
    v4 f1 = *(const v4*)(src + 4);
    bf16x8 pk;
    pk[0] = (__bf16)f0.x; pk[1] = (__bf16)f0.y; pk[2] = (__bf16)f0.z; pk[3] = (__bf16)f0.w;
    pk[4] = (__bf16)f1.x; pk[5] = (__bf16)f1.y; pk[6] = (__bf16)f1.z; pk[7] = (__bf16)f1.w;
    *((bf16x8*)((__bf16*)(ws + WS_BPK)) + o) = pk;
}

// ---------------- kernel 2: fused MFMA GEMM + bias + activations (round-3 body) --
__global__ __launch_bounds__(256) void k_gemm(
    const float* __restrict__ Wih, const float* __restrict__ Whh, const float* __restrict__ bias,
    const float* __restrict__ Wq, const float* __restrict__ Wqb,
    const float* __restrict__ Wk, const float* __restrict__ Wkb,
    const float* __restrict__ Wv, const float* __restrict__ Wvb,
    float* __restrict__ ws) {
    int tid  = threadIdx.x;
    int lane = tid & 63;
    int w    = tid >> 6;          // 0..3
    int t    = blockIdx.x;

    const bf16x8* Bp = (const bf16x8*)((const __bf16*)(ws + WS_BPK));
    __shared__ f32x4 red[4][4][64];   // [wave][b-tile][lane]

    f32x4 a0 = {0.f, 0.f, 0.f, 0.f};
    f32x4 a1 = a0, a2 = a0, a3 = a0;

    if (t < 192) {
        int row = t * 16 + (lane & 15);
        const float* Wb = (w < 2) ? Wih : Whh;
        const float* wrow = Wb + (size_t)row * HD + (lane >> 4) * 8;
        int cofs = (w < 2) ? 0 : -1024;
        int s0 = w * 16;
        #pragma unroll 4
        for (int s = 0; s < 16; ++s) {
            int ks = s0 + s;
            const float* ap = wrow + ks * 32 + cofs;
            v4 f0 = *(const v4*)ap;
            v4 f1 = *(const v4*)(ap + 4);
            bf16x8 a;
            a[0] = (__bf16)f0.x; a[1] = (__bf16)f0.y; a[2] = (__bf16)f0.z; a[3] = (__bf16)f0.w;
            a[4] = (__bf16)f1.x; a[5] = (__bf16)f1.y; a[6] = (__bf16)f1.z; a[7] = (__bf16)f1.w;
            const bf16x8* bb = Bp + (size_t)ks * 256 + lane;
            bf16x8 b0 = bb[0], b1 = bb[64], b2 = bb[128], b3 = bb[192];
            a0 = __builtin_amdgcn_mfma_f32_16x16x32_bf16(a, b0, a0, 0, 0, 0);
            a1 = __builtin_amdgcn_mfma_f32_16x16x32_bf16(a, b1, a1, 0, 0, 0);
            a2 = __builtin_amdgcn_mfma_f32_16x16x32_bf16(a, b2, a2, 0, 0, 0);
            a3 = __builtin_amdgcn_mfma_f32_16x16x32_bf16(a, b3, a3, 0, 0, 0);
        }
    } else {
        int t2  = t - 192;
        int sel = t2 >> 6;
        const float* W = (sel == 0) ? Wq : (sel == 1) ? Wk : Wv;
        int row = (t2 & 63) * 16 + (lane & 15);
        const float* wrow = W + (size_t)row * HD + (lane >> 4) * 8;
        int s0 = w * 8;
        #pragma unroll 4
        for (int s = 0; s < 8; ++s) {
            int ks = s0 + s;
            const float* ap = wrow + ks * 32;
            v4 f0 = *(const v4*)ap;
            v4 f1 = *(const v4*)(ap + 4);
            bf16x8 a;
            a[0] = (__bf16)f0.x; a[1] = (__bf16)f0.y; a[2] = (__bf16)f0.z; a[3] = (__bf16)f0.w;
            a[4] = (__bf16)f1.x; a[5] = (__bf16)f1.y; a[6] = (__bf16)f1.z; a[7] = (__bf16)f1.w;
            const bf16x8* bb = Bp + (size_t)ks * 256 + lane;
            bf16x8 b0 = bb[0], b1 = bb[64], b2 = bb[128], b3 = bb[192];
            a0 = __builtin_amdgcn_mfma_f32_16x16x32_bf16(a, b0, a0, 0, 0, 0);
            a1 = __builtin_amdgcn_mfma_f32_16x16x32_bf16(a, b1, a1, 0, 0, 0);
            a2 = __builtin_amdgcn_mfma_f32_16x16x32_bf16(a, b2, a2, 0, 0, 0);
            a3 = __builtin_amdgcn_mfma_f32_16x16x32_bf16(a, b3, a3, 0, 0, 0);
        }
    }

    red[w][0][lane] = a0;
    red[w][1][lane] = a1;
    red[w][2][lane] = a2;
    red[w][3][lane] = a3;
    __syncthreads();

    int b    = tid & 63;
    int rgrp = tid >> 6;
    int lane2 = (rgrp << 4) | (b & 15);
    int bt    = b >> 4;
    f32x4 s4 = red[0][bt][lane2];
    s4 += red[1][bt][lane2];
    s4 += red[2][bt][lane2];
    s4 += red[3][bt][lane2];

    if (t < 192) {
        int seg  = t >> 6;
        int rloc = (t & 63) * 16 + rgrp * 4;
        int rg   = t * 16 + rgrp * 4;
        if (seg == 0) {
            #pragma unroll
            for (int q = 0; q < 4; ++q)
                ws[WS_IGT + (rloc + q) * 64 + b] = expf(s4[q] + bias[rg + q]);
        } else if (seg == 1) {
            #pragma unroll
            for (int q = 0; q < 4; ++q)
                ws[WS_FGT + (rloc + q) * 64 + b] = expf(s4[q] + bias[rg + q]);
        } else {
            v4 o;
            #pragma unroll
            for (int q = 0; q < 4; ++q) {
                float x = s4[q] + bias[rg + q];
                o[q] = 1.f / (1.f + expf(-x));
            }
            *(v4*)(ws + WS_OGN + b * HD + rloc) = o;
        }
    } else {
        int t2   = t - 192;
        int sel  = t2 >> 6;
        int rloc = (t2 & 63) * 16 + rgrp * 4;
        const float* Bv = (sel == 0) ? Wqb : (sel == 1) ? Wkb : Wvb;
        if (sel == 0) {
            #pragma unroll
            for (int q = 0; q < 4; ++q)
                ws[WS_QT + (rloc + q) * 64 + b] = s4[q] + Bv[rloc + q];
        } else if (sel == 1) {
            v4 kv;
            #pragma unroll
            for (int q = 0; q < 4; ++q) kv[q] = s4[q] + Bv[rloc + q];
            *(v4*)(ws + WS_KN + b * HD + rloc) = kv;
        } else {
            #pragma unroll
            for (int q = 0; q < 4; ++q)
                ws[WS_VT + (rloc + q) * 64 + b] = s4[q] + Bv[rloc + q];
        }
    }
}

// ---------------- kernel 3: C update + fused readout partials -------------------
// INTERLEAVED row mapping: block (b, rg) processes rows i = rg + 32*s, s=0..31.
// At any instant the 32 rg-blocks of a batch collectively cover one contiguous
// 128 KB window sweeping linearly -> dense HBM front (like the 6.5 TB/s fill),
// instead of the previous 4KB-chunks-at-128KB-stride scatter that conflicted on
// HBM channels at every step. NT hints kept (R5 showed worth ~20 us).
// Partial-sum structure unchanged (rows per block = a disjoint 32-row set).
__global__ __launch_bounds__(256) void k_update(const float* __restrict__ C,
                                                float* __restrict__ out,
                                                float* __restrict__ ws) {
    int b  = blockIdx.x >> 5;
    int rg = blockIdx.x & 31;     // row-group: rows i = rg + 32*s
    int tid = threadIdx.x;

    __shared__ float fg_s[32], iv_s[32], q_s[32];
    if (tid < 32) {
        int i = rg + 32 * tid;
        fg_s[tid] = ws[WS_FGT + i * 64 + b];
        iv_s[tid] = ws[WS_IGT + i * 64 + b] * ws[WS_VT + i * 64 + b];
        q_s[tid]  = ws[WS_QT + i * 64 + b];
    }
    __syncthreads();

    v4 k4 = *(const v4*)(ws + WS_KN + b * HD + tid * 4);
    // base at row rg; step between consecutive s is 32 rows = 8192 v4s
    const v4* Cb = (const v4*)(C + (size_t)b * HD * HD) + (size_t)rg * 256 + tid;
    v4*       On = (v4*)(out + NB * HD + (size_t)b * HD * HD) + (size_t)rg * 256 + tid;
    v4 acc0 = {0.f, 0.f, 0.f, 0.f};
    v4 acc1 = {0.f, 0.f, 0.f, 0.f};

    #pragma unroll
    for (int s = 0; s < 32; s += 4) {
        size_t r0 = (size_t)s * 8192;
        v4 c0 = __builtin_nontemporal_load(&Cb[r0]);
        v4 c1 = __builtin_nontemporal_load(&Cb[r0 + 8192]);
        v4 c2 = __builtin_nontemporal_load(&Cb[r0 + 16384]);
        v4 c3 = __builtin_nontemporal_load(&Cb[r0 + 24576]);

        float f0 = fg_s[s + 0], g0 = iv_s[s + 0], q0 = q_s[s + 0];
        float f1 = fg_s[s + 1], g1 = iv_s[s + 1], q1 = q_s[s + 1];
        float f2 = fg_s[s + 2], g2 = iv_s[s + 2], q2 = q_s[s + 2];
        float f3 = fg_s[s + 3], g3 = iv_s[s + 3], q3 = q_s[s + 3];

        v4 n0, n1, n2, n3;
        n0.x = f0 * c0.x + g0 * k4.x; n0.y = f0 * c0.y + g0 * k4.y;
        n0.z = f0 * c0.z + g0 * k4.z; n0.w = f0 * c0.w + g0 * k4.w;
        n1.x = f1 * c1.x + g1 * k4.x; n1.y = f1 * c1.y + g1 * k4.y;
        n1.z = f1 * c1.z + g1 * k4.z; n1.w = f1 * c1.w + g1 * k4.w;
        n2.x = f2 * c2.x + g2 * k4.x; n2.y = f2 * c2.y + g2 * k4.y;
        n2.z = f2 * c2.z + g2 * k4.z; n2.w = f2 * c2.w + g2 * k4.w;
        n3.x = f3 * c3.x + g3 * k4.x; n3.y = f3 * c3.y + g3 * k4.y;
        n3.z = f3 * c3.z + g3 * k4.z; n3.w = f3 * c3.w + g3 * k4.w;

        __builtin_nontemporal_store(n0, &On[r0]);
        __builtin_nontemporal_store(n1, &On[r0 + 8192]);
        __builtin_nontemporal_store(n2, &On[r0 + 16384]);
        __builtin_nontemporal_store(n3, &On[r0 + 24576]);

        acc0.x += q0 * n0.x; acc0.y += q0 * n0.y; acc0.z += q0 * n0.z; acc0.w += q0 * n0.w;
        acc1.x += q1 * n1.x; acc1.y += q1 * n1.y; acc1.z += q1 * n1.z; acc1.w += q1 * n1.w;
        acc0.x += q2 * n2.x; acc0.y += q2 * n2.y; acc0.z += q2 * n2.z; acc0.w += q2 * n2.w;
        acc1.x += q3 * n3.x; acc1.y += q3 * n3.y; acc1.z += q3 * n3.z; acc1.w += q3 * n3.w;
    }
    v4 acc;
    acc.x = acc0.x + acc1.x; acc.y = acc0.y + acc1.y;
    acc.z = acc0.z + acc1.z; acc.w = acc0.w + acc1.w;
    *(v4*)(ws + WS_PART + (size_t)(rg * 64 + b) * HD + tid * 4) = acc;
}

// ---------------- kernel 4: finalize h ------------------------------------------
__global__ __launch_bounds__(256) void k_final(float* __restrict__ out,
                                               const float* __restrict__ ws) {
    int b = blockIdx.x;
    int tid = threadIdx.x;
    const v4* part = (const v4*)(ws + WS_PART);
    v4 s = {0.f, 0.f, 0.f, 0.f};
    #pragma unroll 4
    for (int c = 0; c < 32; ++c) {
        v4 p = part[(size_t)(c * 64 + b) * 256 + tid];
        s.x += p.x; s.y += p.y; s.z += p.z; s.w += p.w;
    }
    v4 o4 = *(const v4*)(ws + WS_OGN + b * HD + tid * 4);
    v4 r;
    r.x = o4.x * s.x; r.y = o4.y * s.y; r.z = o4.z * s.z; r.w = o4.w * s.w;
    *(v4*)(out + b * HD + tid * 4) = r;
}

extern "C" void kernel_launch(void* const* d_in, const int* in_sizes, int n_in,
                              void* d_out, int out_size, void* d_ws, size_t ws_size,
                              hipStream_t stream) {
    const float* input = (const float*)d_in[0];
    const float* h     = (const float*)d_in[1];
    const float* C     = (const float*)d_in[2];
    const float* Wih   = (const float*)d_in[3];
    const float* Whh   = (const float*)d_in[4];
    const float* bias  = (const float*)d_in[5];
    const float* Wq_w  = (const float*)d_in[6];
    const float* Wq_b  = (const float*)d_in[7];
    const float* Wk_w  = (const float*)d_in[8];
    const float* Wk_b  = (const float*)d_in[9];
    const float* Wv_w  = (const float*)d_in[10];
    const float* Wv_b  = (const float*)d_in[11];
    float* out = (float*)d_out;
    float* ws  = (float*)d_ws;

    k_prepb<<<64, 256, 0, stream>>>(input, h, ws);
    k_gemm<<<384, 256, 0, stream>>>(Wih, Whh, bias, Wq_w, Wq_b, Wk_w, Wk_b, Wv_w, Wv_b, ws);
    k_update<<<2048, 256, 0, stream>>>(C, out, ws);
    k_final<<<64, 256, 0, stream>>>(out, ws);
}